// Round 12
// baseline (727.810 us; speedup 1.0000x reference)
//
#include <hip/hip_runtime.h>
#include <math.h>

#define LSEQ 2048
#define DM 512
#define DI 1024
#define NST 16
#define CHUNK 64
#define NC (LSEQ / CHUNK)

__device__ __forceinline__ float siluf(float v) { return v / (1.f + expf(-v)); }

// ---------------- gemm_s: 64x64 tile, 128 threads (2 waves), 4x8 micro, BK=16 ---
// direct write (nz==1) or split-K partials. Measured ~65 TF on MI355X.
__global__ __launch_bounds__(128) void gemm_s(
    const float* __restrict__ A, int lda,
    const float* __restrict__ B, int ldb,
    float* __restrict__ out, int ldc, int Ktot)
{
    __shared__ float As[16][68];
    __shared__ float Bs[16][68];
    const int tid = threadIdx.x;
    const int tx = tid & 7, ty = tid >> 3;
    const int n0 = blockIdx.x << 6, m0 = blockIdx.y << 6;
    const int z = blockIdx.z, nz = gridDim.z;
    const int Kz = Ktot / nz, kb = z * Kz;
    const int arow = tid >> 1, ak = (tid & 1) << 3;
    const int bkr = tid >> 3, bcol = (tid & 7) << 3;
    const float* Ap = A + (size_t)(m0 + arow) * lda + kb + ak;
    const float* Bp = B + (size_t)(kb + bkr) * ldb + n0 + bcol;
    float acc[4][8] = {};
    float4 a0 = *(const float4*)(Ap);
    float4 a1 = *(const float4*)(Ap + 4);
    float4 b0 = *(const float4*)(Bp);
    float4 b1 = *(const float4*)(Bp + 4);
    for (int k0 = 0; k0 < Kz; k0 += 16) {
        As[ak + 0][arow] = a0.x; As[ak + 1][arow] = a0.y;
        As[ak + 2][arow] = a0.z; As[ak + 3][arow] = a0.w;
        As[ak + 4][arow] = a1.x; As[ak + 5][arow] = a1.y;
        As[ak + 6][arow] = a1.z; As[ak + 7][arow] = a1.w;
        *(float4*)&Bs[bkr][bcol] = b0;
        *(float4*)&Bs[bkr][bcol + 4] = b1;
        __syncthreads();
        if (k0 + 16 < Kz) {
            a0 = *(const float4*)(Ap + k0 + 16);
            a1 = *(const float4*)(Ap + k0 + 20);
            b0 = *(const float4*)(Bp + (size_t)(k0 + 16) * ldb);
            b1 = *(const float4*)(Bp + (size_t)(k0 + 16) * ldb + 4);
        }
#pragma unroll
        for (int kk = 0; kk < 16; ++kk) {
            float4 a = *(const float4*)&As[kk][ty << 2];
            float4 bb0 = *(const float4*)&Bs[kk][tx << 3];
            float4 bb1 = *(const float4*)&Bs[kk][(tx << 3) + 4];
            float av[4] = {a.x, a.y, a.z, a.w};
            float bv[8] = {bb0.x, bb0.y, bb0.z, bb0.w, bb1.x, bb1.y, bb1.z, bb1.w};
#pragma unroll
            for (int i = 0; i < 4; ++i)
#pragma unroll
                for (int j = 0; j < 8; ++j)
                    acc[i][j] = fmaf(av[i], bv[j], acc[i][j]);
        }
        __syncthreads();
    }
    const int Mtot = gridDim.y << 6;
    float* op = out + (size_t)z * Mtot * ldc;
#pragma unroll
    for (int i = 0; i < 4; ++i) {
        float* Cp = op + (size_t)(m0 + (ty << 2) + i) * ldc + n0 + (tx << 3);
        *(float4*)Cp = make_float4(acc[i][0], acc[i][1], acc[i][2], acc[i][3]);
        *(float4*)(Cp + 4) = make_float4(acc[i][4], acc[i][5], acc[i][6], acc[i][7]);
    }
}

// ---------------- gemm_w: 128(M)x64(N) tile, 128 thr, 8x8 micro, BK=16 ----------
__global__ __launch_bounds__(128) void gemm_w(
    const float* __restrict__ A, int lda,
    const float* __restrict__ B, int ldb,
    float* __restrict__ out, int ldc, int Ktot)
{
    __shared__ float As[16][192];
    __shared__ float Bs[16][68];
    const int tid = threadIdx.x;
    const int tx = tid & 7, ty = tid >> 3;
    const int n0 = blockIdx.x << 6, m0 = blockIdx.y << 7;
    const int z = blockIdx.z, nz = gridDim.z;
    const int Kz = Ktot / nz, kb = z * Kz;
    const int apos = ((tid >> 3) * 12) + (tid & 7);
    const int bkr = tid >> 3, bcol = (tid & 7) << 3;
    const float* Ap = A + (size_t)(m0 + tid) * lda + kb;
    const float* Bp = B + (size_t)(kb + bkr) * ldb + n0 + bcol;
    float acc[8][8] = {};
    float4 a0 = *(const float4*)(Ap + 0);
    float4 a1 = *(const float4*)(Ap + 4);
    float4 a2 = *(const float4*)(Ap + 8);
    float4 a3 = *(const float4*)(Ap + 12);
    float4 b0 = *(const float4*)(Bp + 0);
    float4 b1 = *(const float4*)(Bp + 4);
    for (int k0 = 0; k0 < Kz; k0 += 16) {
        As[0][apos] = a0.x;  As[1][apos] = a0.y;  As[2][apos] = a0.z;  As[3][apos] = a0.w;
        As[4][apos] = a1.x;  As[5][apos] = a1.y;  As[6][apos] = a1.z;  As[7][apos] = a1.w;
        As[8][apos] = a2.x;  As[9][apos] = a2.y;  As[10][apos] = a2.z; As[11][apos] = a2.w;
        As[12][apos] = a3.x; As[13][apos] = a3.y; As[14][apos] = a3.z; As[15][apos] = a3.w;
        *(float4*)&Bs[bkr][bcol] = b0;
        *(float4*)&Bs[bkr][bcol + 4] = b1;
        __syncthreads();
        if (k0 + 16 < Kz) {
            a0 = *(const float4*)(Ap + k0 + 16);
            a1 = *(const float4*)(Ap + k0 + 20);
            a2 = *(const float4*)(Ap + k0 + 24);
            a3 = *(const float4*)(Ap + k0 + 28);
            b0 = *(const float4*)(Bp + (size_t)(k0 + 16) * ldb);
            b1 = *(const float4*)(Bp + (size_t)(k0 + 16) * ldb + 4);
        }
#pragma unroll
        for (int kk = 0; kk < 16; ++kk) {
            float4 av0 = *(const float4*)&As[kk][ty * 12];
            float4 av1 = *(const float4*)&As[kk][ty * 12 + 4];
            float4 bv0 = *(const float4*)&Bs[kk][tx << 3];
            float4 bv1 = *(const float4*)&Bs[kk][(tx << 3) + 4];
            float a8[8] = {av0.x, av0.y, av0.z, av0.w, av1.x, av1.y, av1.z, av1.w};
            float b8[8] = {bv0.x, bv0.y, bv0.z, bv0.w, bv1.x, bv1.y, bv1.z, bv1.w};
#pragma unroll
            for (int i = 0; i < 8; ++i)
#pragma unroll
                for (int j = 0; j < 8; ++j)
                    acc[i][j] = fmaf(a8[i], b8[j], acc[i][j]);
        }
        __syncthreads();
    }
    const int Mtot = gridDim.y << 7;
    float* op = out + (size_t)z * Mtot * ldc;
#pragma unroll
    for (int i = 0; i < 8; ++i) {
        float* Cp = op + (size_t)(m0 + (ty << 3) + i) * ldc + n0 + (tx << 3);
        *(float4*)Cp = make_float4(acc[i][0], acc[i][1], acc[i][2], acc[i][3]);
        *(float4*)(Cp + 4) = make_float4(acc[i][4], acc[i][5], acc[i][6], acc[i][7]);
    }
}

// ---------------- dt_proj fused: delta = softplus(dbc[:, :32] @ dt_w + dt_b) ----
__global__ __launch_bounds__(256) void dtproj_k(
    const float* __restrict__ A, const float* __restrict__ B,
    const float* __restrict__ dtb, float* __restrict__ delta)
{
    __shared__ float As[16][68];
    __shared__ float Bs[16][68];
    const int tid = threadIdx.x;
    const int tx = tid & 15, ty = tid >> 4;
    const int m0 = blockIdx.y << 6, n0 = blockIdx.x << 6;
    const int arow = tid >> 2, akk = (tid & 3) << 2;
    const int bkr = tid >> 4, bnn = (tid & 15) << 2;
    const float* Ap = A + (size_t)(m0 + arow) * 64 + akk;
    const float* Bp = B + (size_t)bkr * DI + n0 + bnn;
    float acc[4][4] = {};
    for (int k0 = 0; k0 < 32; k0 += 16) {
        float4 av = *(const float4*)(Ap + k0);
        float4 bv = *(const float4*)(Bp + (size_t)k0 * DI);
        As[akk + 0][arow] = av.x;
        As[akk + 1][arow] = av.y;
        As[akk + 2][arow] = av.z;
        As[akk + 3][arow] = av.w;
        *(float4*)&Bs[bkr][bnn] = bv;
        __syncthreads();
#pragma unroll
        for (int kk = 0; kk < 16; ++kk) {
            float4 a = *(const float4*)&As[kk][ty << 2];
            float4 b = *(const float4*)&Bs[kk][tx << 2];
#pragma unroll
            for (int i = 0; i < 4; ++i) {
                float ai = (i == 0) ? a.x : (i == 1) ? a.y : (i == 2) ? a.z : a.w;
                acc[i][0] = fmaf(ai, b.x, acc[i][0]);
                acc[i][1] = fmaf(ai, b.y, acc[i][1]);
                acc[i][2] = fmaf(ai, b.z, acc[i][2]);
                acc[i][3] = fmaf(ai, b.w, acc[i][3]);
            }
        }
        __syncthreads();
    }
    const int col = n0 + (tx << 2);
    float4 bb = *(const float4*)&dtb[col];
    float bias[4] = {bb.x, bb.y, bb.z, bb.w};
#pragma unroll
    for (int i = 0; i < 4; ++i) {
        float* Cp = delta + (size_t)(m0 + (ty << 2) + i) * DI + col;
#pragma unroll
        for (int j = 0; j < 4; ++j) {
            float v = acc[i][j] + bias[j];
            Cp[j] = fmaxf(v, 0.f) + log1pf(expf(-fabsf(v)));
        }
    }
}

// ---------------- generic fp32 GEMM: 64x64 tile, 4x4 micro, BK=16 ---------------
__global__ __launch_bounds__(256) void gemm64(
    const float* __restrict__ A, int lda,
    const float* __restrict__ B, int ldb,
    float* __restrict__ C, int ldc,
    int K, int accum)
{
    __shared__ float As[16][68];
    __shared__ float Bs[16][68];
    const int tid = threadIdx.x;
    const int tx = tid & 15, ty = tid >> 4;
    const int m0 = blockIdx.y << 6, n0 = blockIdx.x << 6;
    const int arow = tid >> 2, akk = (tid & 3) << 2;
    const int bkr = tid >> 4, bnn = (tid & 15) << 2;
    const float* Ap = A + (size_t)(m0 + arow) * lda + akk;
    const float* Bp = B + (size_t)bkr * ldb + n0 + bnn;
    float acc[4][4] = {};
    for (int k0 = 0; k0 < K; k0 += 16) {
        float4 av = *(const float4*)(Ap + k0);
        float4 bv = *(const float4*)(Bp + (size_t)k0 * ldb);
        As[akk + 0][arow] = av.x;
        As[akk + 1][arow] = av.y;
        As[akk + 2][arow] = av.z;
        As[akk + 3][arow] = av.w;
        *(float4*)&Bs[bkr][bnn] = bv;
        __syncthreads();
#pragma unroll
        for (int kk = 0; kk < 16; ++kk) {
            float4 a = *(const float4*)&As[kk][ty << 2];
            float4 b = *(const float4*)&Bs[kk][tx << 2];
            acc[0][0] = fmaf(a.x, b.x, acc[0][0]);
            acc[0][1] = fmaf(a.x, b.y, acc[0][1]);
            acc[0][2] = fmaf(a.x, b.z, acc[0][2]);
            acc[0][3] = fmaf(a.x, b.w, acc[0][3]);
            acc[1][0] = fmaf(a.y, b.x, acc[1][0]);
            acc[1][1] = fmaf(a.y, b.y, acc[1][1]);
            acc[1][2] = fmaf(a.y, b.z, acc[1][2]);
            acc[1][3] = fmaf(a.y, b.w, acc[1][3]);
            acc[2][0] = fmaf(a.z, b.x, acc[2][0]);
            acc[2][1] = fmaf(a.z, b.y, acc[2][1]);
            acc[2][2] = fmaf(a.z, b.z, acc[2][2]);
            acc[2][3] = fmaf(a.z, b.w, acc[2][3]);
            acc[3][0] = fmaf(a.w, b.x, acc[3][0]);
            acc[3][1] = fmaf(a.w, b.y, acc[3][1]);
            acc[3][2] = fmaf(a.w, b.z, acc[3][2]);
            acc[3][3] = fmaf(a.w, b.w, acc[3][3]);
        }
        __syncthreads();
    }
#pragma unroll
    for (int i = 0; i < 4; ++i) {
        float* Cp = C + (size_t)(m0 + (ty << 2) + i) * ldc + n0 + (tx << 2);
        if (accum) {
            Cp[0] += acc[i][0]; Cp[1] += acc[i][1]; Cp[2] += acc[i][2]; Cp[3] += acc[i][3];
        } else {
            Cp[0] = acc[i][0]; Cp[1] = acc[i][1]; Cp[2] = acc[i][2]; Cp[3] = acc[i][3];
        }
    }
}

// ---------------- x_proj split-K: [2048,1024]@[1024,64] -> partials -------------
__global__ __launch_bounds__(256) void xproj_splitk(
    const float* __restrict__ A, const float* __restrict__ B,
    float* __restrict__ part)
{
    __shared__ float As[16][68];
    __shared__ float Bs[16][68];
    const int tid = threadIdx.x;
    const int tx = tid & 15, ty = tid >> 4;
    const int ks = blockIdx.x;
    const int m0 = blockIdx.y << 6;
    const int arow = tid >> 2, ak = (tid & 3) << 2;
    const int bkr = tid >> 4, bcol = (tid & 15) << 2;
    const int kbase = ks << 7;
    const float* Ap = A + (size_t)(m0 + arow) * DI + kbase + ak;
    const float* Bp = B + (size_t)(kbase + bkr) * 64 + bcol;
    float acc[4][4] = {};
    for (int k0 = 0; k0 < 128; k0 += 16) {
        float4 av = *(const float4*)(Ap + k0);
        float4 bv = *(const float4*)(Bp + k0 * 64);
        As[ak + 0][arow] = av.x;
        As[ak + 1][arow] = av.y;
        As[ak + 2][arow] = av.z;
        As[ak + 3][arow] = av.w;
        *(float4*)&Bs[bkr][bcol] = bv;
        __syncthreads();
#pragma unroll
        for (int kk = 0; kk < 16; ++kk) {
            float4 a = *(const float4*)&As[kk][ty << 2];
            float4 b = *(const float4*)&Bs[kk][tx << 2];
            acc[0][0] = fmaf(a.x, b.x, acc[0][0]);
            acc[0][1] = fmaf(a.x, b.y, acc[0][1]);
            acc[0][2] = fmaf(a.x, b.z, acc[0][2]);
            acc[0][3] = fmaf(a.x, b.w, acc[0][3]);
            acc[1][0] = fmaf(a.y, b.x, acc[1][0]);
            acc[1][1] = fmaf(a.y, b.y, acc[1][1]);
            acc[1][2] = fmaf(a.y, b.z, acc[1][2]);
            acc[1][3] = fmaf(a.y, b.w, acc[1][3]);
            acc[2][0] = fmaf(a.z, b.x, acc[2][0]);
            acc[2][1] = fmaf(a.z, b.y, acc[2][1]);
            acc[2][2] = fmaf(a.z, b.z, acc[2][2]);
            acc[2][3] = fmaf(a.z, b.w, acc[2][3]);
            acc[3][0] = fmaf(a.w, b.x, acc[3][0]);
            acc[3][1] = fmaf(a.w, b.y, acc[3][1]);
            acc[3][2] = fmaf(a.w, b.z, acc[3][2]);
            acc[3][3] = fmaf(a.w, b.w, acc[3][3]);
        }
        __syncthreads();
    }
#pragma unroll
    for (int i = 0; i < 4; ++i) {
        float* Cp = part + ((size_t)ks * LSEQ + m0 + (ty << 2) + i) * 64 + (tx << 2);
        Cp[0] = acc[i][0]; Cp[1] = acc[i][1]; Cp[2] = acc[i][2]; Cp[3] = acc[i][3];
    }
}

__global__ __launch_bounds__(256) void xproj_reduce(
    const float* __restrict__ part, float* __restrict__ dbc)
{
    const int idx = blockIdx.x * 256 + threadIdx.x;   // LSEQ*64
    float s = 0.f;
#pragma unroll
    for (int ks = 0; ks < 8; ++ks) s += part[(size_t)ks * LSEQ * 64 + idx];
    dbc[idx] = s;
}

// ---------------- fc1_fin: sk-reduce(8) + bias + GELU + pos + RMS ---------------
__global__ __launch_bounds__(256) void fc1_fin(
    const float* __restrict__ part,
    const float* __restrict__ bfc1, const float* __restrict__ coords,
    const float* __restrict__ Wpos, const float* __restrict__ bpos,
    const float* __restrict__ rw,
    float* __restrict__ h, float* __restrict__ hn)
{
    const int t = blockIdx.x, tid = threadIdx.x;
    const size_t base = (size_t)t * DM;
    float va = 0.f, vb = 0.f;
#pragma unroll
    for (int z = 0; z < 8; ++z) {
        va += part[(size_t)z * LSEQ * DM + base + tid];
        vb += part[(size_t)z * LSEQ * DM + base + 256 + tid];
    }
    const float cx = coords[2 * t], cy = coords[2 * t + 1];
    va += bfc1[tid];
    vb += bfc1[256 + tid];
    float ga = 0.5f * va * (1.f + erff(va * 0.70710678118654752f));
    float gb = 0.5f * vb * (1.f + erff(vb * 0.70710678118654752f));
    ga += cx * Wpos[tid] + cy * Wpos[DM + tid] + bpos[tid];
    gb += cx * Wpos[256 + tid] + cy * Wpos[DM + 256 + tid] + bpos[256 + tid];
    h[base + tid] = ga;
    h[base + 256 + tid] = gb;
    float ss = ga * ga + gb * gb;
#pragma unroll
    for (int off = 1; off < 64; off <<= 1) ss += __shfl_xor(ss, off);
    __shared__ float red[4];
    if ((tid & 63) == 0) red[tid >> 6] = ss;
    __syncthreads();
    float inv = rsqrtf((red[0] + red[1] + red[2] + red[3]) * (1.f / DM) + 1e-5f);
    hn[base + tid] = ga * inv * rw[tid];
    hn[base + 256 + tid] = gb * inv * rw[256 + tid];
}

// ---------------- skadd_norm: h += sum_z(8) part[z]; then RMS or LN -------------
__global__ __launch_bounds__(256) void skadd_norm(
    const float* __restrict__ part, float* __restrict__ h,
    const float* __restrict__ w1, const float* __restrict__ b1,
    float* __restrict__ outb, int mode)
{
    const int t = blockIdx.x, tid = threadIdx.x;
    const size_t base = (size_t)t * DM;
    float va = h[base + tid], vb = h[base + 256 + tid];
#pragma unroll
    for (int z = 0; z < 8; ++z) {
        va += part[(size_t)z * LSEQ * DM + base + tid];
        vb += part[(size_t)z * LSEQ * DM + base + 256 + tid];
    }
    h[base + tid] = va;
    h[base + 256 + tid] = vb;
    __shared__ float red1[4], red2[4];
    if (mode == 0) {
        float ss = va * va + vb * vb;
#pragma unroll
        for (int off = 1; off < 64; off <<= 1) ss += __shfl_xor(ss, off);
        if ((tid & 63) == 0) red1[tid >> 6] = ss;
        __syncthreads();
        float inv = rsqrtf((red1[0] + red1[1] + red1[2] + red1[3]) * (1.f / DM) + 1e-5f);
        outb[base + tid] = va * inv * w1[tid];
        outb[base + 256 + tid] = vb * inv * w1[256 + tid];
    } else {
        float s = va + vb;
#pragma unroll
        for (int off = 1; off < 64; off <<= 1) s += __shfl_xor(s, off);
        if ((tid & 63) == 0) red1[tid >> 6] = s;
        __syncthreads();
        float mean = (red1[0] + red1[1] + red1[2] + red1[3]) * (1.f / DM);
        float da = va - mean, db = vb - mean;
        float vs = da * da + db * db;
#pragma unroll
        for (int off = 1; off < 64; off <<= 1) vs += __shfl_xor(vs, off);
        if ((tid & 63) == 0) red2[tid >> 6] = vs;
        __syncthreads();
        float inv = rsqrtf((red2[0] + red2[1] + red2[2] + red2[3]) * (1.f / DM) + 1e-5f);
        outb[base + tid] = da * inv * w1[tid] + b1[tid];
        outb[base + 256 + tid] = db * inv * w1[256 + tid] + b1[256 + tid];
    }
}

// ---------------- causal depthwise conv (k=4) + SiLU ----------------------------
__global__ __launch_bounds__(256) void conv_silu_k(
    const float* __restrict__ xz, const float* __restrict__ cw,
    const float* __restrict__ cb, float* __restrict__ xc)
{
    int idx = blockIdx.x * 256 + threadIdx.x;   // L*DI
    int t = idx >> 10, c = idx & 1023;
    float w0 = cw[c * 4], w1 = cw[c * 4 + 1], w2 = cw[c * 4 + 2], w3 = cw[c * 4 + 3];
    float s = cb[c];
    if (t >= 3) s = fmaf(xz[(size_t)(t - 3) * 2048 + c], w0, s);
    if (t >= 2) s = fmaf(xz[(size_t)(t - 2) * 2048 + c], w1, s);
    if (t >= 1) s = fmaf(xz[(size_t)(t - 1) * 2048 + c], w2, s);
    s = fmaf(xz[(size_t)t * 2048 + c], w3, s);
    xc[idx] = siluf(s);
}

// ===================== state-in-register chunked selective scan =================
// Thread owns channel d with all 16 states in registers. delta/x/z stream from
// global (coalesced, prefetch-1); B/C broadcast from small LDS tile.
// Summaries laid out [c][n][d] for coalesced I/O.
__global__ __launch_bounds__(128) void scan_p1(
    const float* __restrict__ delta, const float* __restrict__ xc,
    const float* __restrict__ dbc, const float* __restrict__ alog,
    float* __restrict__ aprod, float* __restrict__ hfin)
{
    __shared__ float sB[CHUNK][16];
    const int tid = threadIdx.x;
    const int d = (blockIdx.x << 7) + tid;
    const int c = blockIdx.y;
    const int t0 = c * CHUNK;
    for (int i = tid; i < CHUNK * 16; i += 128)
        sB[i >> 4][i & 15] = dbc[(size_t)(t0 + (i >> 4)) * 64 + 32 + (i & 15)];
    float An[NST];
#pragma unroll
    for (int n = 0; n < NST; ++n) An[n] = -expf(alog[d * NST + n]);
    __syncthreads();
    float h[NST] = {}, ap[NST];
#pragma unroll
    for (int n = 0; n < NST; ++n) ap[n] = 1.f;
    float dl = delta[(size_t)t0 * DI + d];
    float xv = xc[(size_t)t0 * DI + d];
    for (int i = 0; i < CHUNK; ++i) {
        float dln = 0.f, xvn = 0.f;
        if (i + 1 < CHUNK) {
            dln = delta[(size_t)(t0 + i + 1) * DI + d];
            xvn = xc[(size_t)(t0 + i + 1) * DI + d];
        }
        const float dlx = dl * xv;
        float4 b0 = *(const float4*)&sB[i][0];
        float4 b1 = *(const float4*)&sB[i][4];
        float4 b2 = *(const float4*)&sB[i][8];
        float4 b3 = *(const float4*)&sB[i][12];
        float Bv[NST] = {b0.x, b0.y, b0.z, b0.w, b1.x, b1.y, b1.z, b1.w,
                         b2.x, b2.y, b2.z, b2.w, b3.x, b3.y, b3.z, b3.w};
#pragma unroll
        for (int n = 0; n < NST; ++n) {
            float a = expf(dl * An[n]);
            h[n] = fmaf(a, h[n], dlx * Bv[n]);
            ap[n] *= a;
        }
        dl = dln; xv = xvn;
    }
#pragma unroll
    for (int n = 0; n < NST; ++n) {
        aprod[((size_t)c * NST + n) * DI + d] = ap[n];
        hfin[((size_t)c * NST + n) * DI + d] = h[n];
    }
}

__global__ __launch_bounds__(256) void scan_carry(
    const float* __restrict__ aprod, const float* __restrict__ hfin,
    float* __restrict__ carry)
{
    const int idx = blockIdx.x * 256 + threadIdx.x;   // NST*DI = 16384
    float h = 0.f;
    carry[idx] = 0.f;
    for (int c = 0; c < NC - 1; ++c) {
        h = fmaf(aprod[(size_t)c * NST * DI + idx], h, hfin[(size_t)c * NST * DI + idx]);
        carry[(size_t)(c + 1) * NST * DI + idx] = h;
    }
}

__global__ __launch_bounds__(128) void scan_p2(
    const float* __restrict__ delta, const float* __restrict__ xc,
    const float* __restrict__ dbc, const float* __restrict__ xz,
    const float* __restrict__ alog, const float* __restrict__ Dp,
    const float* __restrict__ carry, float* __restrict__ y)
{
    __shared__ float sB[CHUNK][16];
    __shared__ float sC[CHUNK][16];
    const int tid = threadIdx.x;
    const int d = (blockIdx.x << 7) + tid;
    const int c = blockIdx.y;
    const int t0 = c * CHUNK;
    for (int i = tid; i < CHUNK * 16; i += 128) {
        sB[i >> 4][i & 15] = dbc[(size_t)(t0 + (i >> 4)) * 64 + 32 + (i & 15)];
        sC[i >> 4][i & 15] = dbc[(size_t)(t0 + (i >> 4)) * 64 + 48 + (i & 15)];
    }
    float An[NST];
#pragma unroll
    for (int n = 0; n < NST; ++n) An[n] = -expf(alog[d * NST + n]);
    const float Dd = Dp[d];
    float h[NST];
#pragma unroll
    for (int n = 0; n < NST; ++n) h[n] = carry[((size_t)c * NST + n) * DI + d];
    __syncthreads();
    float dl = delta[(size_t)t0 * DI + d];
    float xv = xc[(size_t)t0 * DI + d];
    float zz = xz[(size_t)t0 * 2048 + 1024 + d];
    for (int i = 0; i < CHUNK; ++i) {
        float dln = 0.f, xvn = 0.f, zzn = 0.f;
        if (i + 1 < CHUNK) {
            dln = delta[(size_t)(t0 + i + 1) * DI + d];
            xvn = xc[(size_t)(t0 + i + 1) * DI + d];
            zzn = xz[(size_t)(t0 + i + 1) * 2048 + 1024 + d];
        }
        const float dlx = dl * xv;
        float4 b0 = *(const float4*)&sB[i][0];
        float4 b1 = *(const float4*)&sB[i][4];
        float4 b2 = *(const float4*)&sB[i][8];
        float4 b3 = *(const float4*)&sB[i][12];
        float4 c0 = *(const float4*)&sC[i][0];
        float4 c1 = *(const float4*)&sC[i][4];
        float4 c2 = *(const float4*)&sC[i][8];
        float4 c3 = *(const float4*)&sC[i][12];
        float Bv[NST] = {b0.x, b0.y, b0.z, b0.w, b1.x, b1.y, b1.z, b1.w,
                         b2.x, b2.y, b2.z, b2.w, b3.x, b3.y, b3.z, b3.w};
        float Cv[NST] = {c0.x, c0.y, c0.z, c0.w, c1.x, c1.y, c1.z, c1.w,
                         c2.x, c2.y, c2.z, c2.w, c3.x, c3.y, c3.z, c3.w};
        float p = 0.f;
#pragma unroll
        for (int n = 0; n < NST; ++n) {
            float a = expf(dl * An[n]);
            h[n] = fmaf(a, h[n], dlx * Bv[n]);
            p = fmaf(h[n], Cv[n], p);
        }
        y[(size_t)(t0 + i) * DI + d] = (p + xv * Dd) * siluf(zz);
        dl = dln; xv = xvn; zz = zzn;
    }
}

// ---------------- attn epilogue: scores = tanh(amx+ba1)@Wa2 + ba2 ---------------
__global__ __launch_bounds__(256) void attn_fin(
    const float* __restrict__ amx, const float* __restrict__ ba1,
    const float* __restrict__ Wa2, const float* __restrict__ ba2,
    float* __restrict__ scores)
{
    const int tid = threadIdx.x;
    const int row = blockIdx.x * 4 + (tid >> 6);
    const int lane = tid & 63;
    float v = tanhf(amx[(size_t)row * 128 + lane] + ba1[lane]) * Wa2[lane]
            + tanhf(amx[(size_t)row * 128 + 64 + lane] + ba1[64 + lane]) * Wa2[64 + lane];
#pragma unroll
    for (int off = 1; off < 64; off <<= 1) v += __shfl_xor(v, off);
    if (lane == 0) scores[row] = v + ba2[0];
}

// ---------------- softmax over 2048 scores (one block) --------------------------
__global__ __launch_bounds__(1024) void softmax_k(
    const float* __restrict__ s, float* __restrict__ w)
{
    const int tid = threadIdx.x;
    __shared__ float red[16];
    float m = fmaxf(s[tid], s[tid + 1024]);
#pragma unroll
    for (int off = 1; off < 64; off <<= 1) m = fmaxf(m, __shfl_xor(m, off));
    if ((tid & 63) == 0) red[tid >> 6] = m;
    __syncthreads();
    if (tid < 64) {
        float mm = (tid < 16) ? red[tid] : -1e30f;
#pragma unroll
        for (int off = 1; off < 16; off <<= 1) mm = fmaxf(mm, __shfl_xor(mm, off));
        if (tid == 0) red[0] = mm;
    }
    __syncthreads();
    const float gm = red[0];
    __syncthreads();
    float e0 = expf(s[tid] - gm), e1 = expf(s[tid + 1024] - gm);
    float sum = e0 + e1;
#pragma unroll
    for (int off = 1; off < 64; off <<= 1) sum += __shfl_xor(sum, off);
    __shared__ float red2[16];
    if ((tid & 63) == 0) red2[tid >> 6] = sum;
    __syncthreads();
    if (tid < 64) {
        float ss = (tid < 16) ? red2[tid] : 0.f;
#pragma unroll
        for (int off = 1; off < 16; off <<= 1) ss += __shfl_xor(ss, off);
        if (tid == 0) red2[0] = ss;
    }
    __syncthreads();
    float inv = 1.f / red2[0];
    w[tid] = e0 * inv;
    w[tid + 1024] = e1 * inv;
}

// ---------------- pooled: two-stage  part[tc,j] then sum ------------------------
__global__ __launch_bounds__(256) void pooled_p1(
    const float* __restrict__ wts, const float* __restrict__ hf, float* __restrict__ part)
{
    const int j = blockIdx.x * 256 + threadIdx.x;   // 0..511
    const int tc = blockIdx.y;                       // 16 chunks of 128
    float acc = 0.f;
    const int t0 = tc * 128;
    for (int t = t0; t < t0 + 128; ++t) acc = fmaf(wts[t], hf[(size_t)t * DM + j], acc);
    part[(size_t)tc * DM + j] = acc;
}

__global__ __launch_bounds__(256) void pooled_p2(
    const float* __restrict__ part, float* __restrict__ pooled)
{
    const int j = blockIdx.x * 256 + threadIdx.x;
    float acc = 0.f;
#pragma unroll
    for (int tc = 0; tc < 16; ++tc) acc += part[(size_t)tc * DM + j];
    pooled[j] = acc;
}

// ---------------- ct1: ConvT 1x1->4x4 (s=1,p=0), 512->256, relu -----------------
__global__ __launch_bounds__(256) void ct1_fast(
    const float* __restrict__ feat, const float* __restrict__ w,
    const float* __restrict__ b, float* __restrict__ out)
{
    __shared__ float sf[512];
    __shared__ float sRed[256];
    const int o = blockIdx.x, tid = threadIdx.x;
    sf[tid] = feat[tid];
    sf[tid + 256] = feat[tid + 256];
    __syncthreads();
    const int p = tid & 15, g = tid >> 4;
    float acc = 0.f;
#pragma unroll 8
    for (int ci = g * 32; ci < g * 32 + 32; ++ci)
        acc = fmaf(sf[ci], w[ci * 4096 + (o << 4) + p], acc);
    sRed[tid] = acc;
    __syncthreads();
    if (g == 0) {
        float s = b[o];
#pragma unroll
        for (int gg = 0; gg < 16; ++gg) s += sRed[gg * 16 + p];
        out[(o << 4) + p] = fmaxf(s, 0.f);
    }
}

// ---------------- ct2: ConvT 4x4->16x16 (s=4,p=0), 256->128, relu ---------------
__global__ __launch_bounds__(256) void ct2_fast(
    const float* __restrict__ in, const float* __restrict__ w,
    const float* __restrict__ b, float* __restrict__ out)
{
    __shared__ float sI[1024];
    __shared__ float sW[1024];
    __shared__ float sRed[256];
    const int yy = blockIdx.x, o = blockIdx.y, tid = threadIdx.x;
    const int iy = yy >> 2, ky = yy & 3;
    for (int i = tid; i < 1024; i += 256) {
        int ci = i >> 2, q = i & 3;
        sI[i] = in[(ci << 4) + (iy << 2) + q];
        sW[i] = w[ci * 2048 + (o << 4) + (ky << 2) + q];
    }
    __syncthreads();
    const int xx = tid & 15, g = tid >> 4;
    const int ix = xx >> 2, kx = xx & 3;
    float acc = 0.f;
#pragma unroll 8
    for (int ci = g * 16; ci < g * 16 + 16; ++ci)
        acc = fmaf(sI[(ci << 2) + ix], sW[(ci << 2) + kx], acc);
    sRed[tid] = acc;
    __syncthreads();
    if (g == 0) {
        float s = b[o];
#pragma unroll
        for (int gg = 0; gg < 16; ++gg) s += sRed[gg * 16 + xx];
        out[(o << 8) + (yy << 4) + xx] = fmaxf(s, 0.f);
    }
}

// ---------------- ConvT (k=4,s=2,p=1) Hin->2*Hin, LDS-staged --------------------
__global__ __launch_bounds__(256) void ctup_fast(
    const float* __restrict__ in, const float* __restrict__ w,
    const float* __restrict__ b, float* __restrict__ out,
    int Cin, int Cout, int Hin, int hshift, int relu)
{
    __shared__ float sIn[4608];
    __shared__ float sW[2048];
    __shared__ float sRed[256];
    const int tid = threadIdx.x;
    const int yy = blockIdx.x, o = blockIdx.y;
    const int Hout = Hin << 1;
    const int ST = Hin + 2;
    const int houtshift = hshift + 1;

    const int ky0 = (yy + 1) & 1;
    const int iy0 = (yy + 1 - ky0) >> 1;
    const int iy1 = iy0 - 1;
    const int row_elems = Cin * ST;

    for (int i = tid; i < 2 * row_elems; i += 256) sIn[i] = 0.f;
    __syncthreads();
    const int nload = Cin << hshift;
    if (iy0 < Hin) {
        const float* src = in + ((size_t)iy0 << hshift);
        for (int i = tid; i < nload; i += 256) {
            int ci = i >> hshift, col = i & (Hin - 1);
            sIn[ci * ST + 1 + col] = src[((size_t)ci << (2 * hshift)) + col];
        }
    }
    if (iy1 >= 0) {
        const float* src = in + ((size_t)iy1 << hshift);
        for (int i = tid; i < nload; i += 256) {
            int ci = i >> hshift, col = i & (Hin - 1);
            sIn[row_elems + ci * ST + 1 + col] = src[((size_t)ci << (2 * hshift)) + col];
        }
    }
    for (int i = tid; i < (Cin << 4); i += 256)
        sW[i] = w[(size_t)(i >> 4) * (Cout << 4) + (o << 4) + (i & 15)];
    __syncthreads();

    const int xx = tid & (Hout - 1);
    const int g = tid >> houtshift;
    const int kx0 = (xx + 1) & 1;
    const int ix0 = (xx + 1 - kx0) >> 1;
    const int k00 = (ky0 << 2) + kx0;

    float acc = 0.f;
    const float* in1 = sIn + row_elems;
#pragma unroll 4
    for (int ci = g * 16; ci < g * 16 + 16; ++ci) {
        const int base = ci * ST + ix0;
        const float* wr = &sW[ci << 4];
        float i00 = sIn[base + 1], i01 = sIn[base];
        float i10 = in1[base + 1], i11 = in1[base];
        acc = fmaf(i00, wr[k00], acc);
        acc = fmaf(i01, wr[k00 + 2], acc);
        acc = fmaf(i10, wr[k00 + 8], acc);
        acc = fmaf(i11, wr[k00 + 10], acc);
    }
    sRed[tid] = acc;
    __syncthreads();
    if (g == 0) {
        float s = b[o];
        const int XG = 256 >> houtshift;
        for (int gg = 0; gg < XG; ++gg) s += sRed[(gg << houtshift) + xx];
        out[(size_t)o * Hout * Hout + (size_t)yy * Hout + xx] = relu ? fmaxf(s, 0.f) : s;
    }
}

extern "C" void kernel_launch(void* const* d_in, const int* in_sizes, int n_in,
                              void* d_out, int out_size, void* d_ws, size_t ws_size,
                              hipStream_t stream)
{
    const float* x      = (const float*)d_in[0];
    const float* coords = (const float*)d_in[1];
    const float* Wfc1   = (const float*)d_in[2];
    const float* bfc1   = (const float*)d_in[3];
    const float* Wpos   = (const float*)d_in[4];
    const float* bpos   = (const float*)d_in[5];
    const float* in_w   = (const float*)d_in[6];
    const float* conv_w = (const float*)d_in[7];
    const float* conv_b = (const float*)d_in[8];
    const float* x_w    = (const float*)d_in[9];
    const float* dt_w   = (const float*)d_in[10];
    const float* dt_b   = (const float*)d_in[11];
    const float* A_log  = (const float*)d_in[12];
    const float* Dp     = (const float*)d_in[13];
    const float* out_w  = (const float*)d_in[14];
    const float* rms_w  = (const float*)d_in[15];
    const float* ln_w   = (const float*)d_in[16];
    const float* ln_b   = (const float*)d_in[17];
    const float* Wa1    = (const float*)d_in[18];
    const float* ba1    = (const float*)d_in[19];
    const float* Wa2    = (const float*)d_in[20];
    const float* ba2    = (const float*)d_in[21];
    const float* ct1w   = (const float*)d_in[22];
    const float* ct1b   = (const float*)d_in[23];
    const float* ct2w   = (const float*)d_in[24];
    const float* ct2b   = (const float*)d_in[25];
    const float* ct3w   = (const float*)d_in[26];
    const float* ct3b   = (const float*)d_in[27];
    const float* ct4w   = (const float*)d_in[28];
    const float* ct4b   = (const float*)d_in[29];
    const float* ct5w   = (const float*)d_in[30];
    const float* ct5b   = (const float*)d_in[31];

    // workspace layout (floats)
    float* ws     = (float*)d_ws;
    float* h      = ws;                         // L*DM
    float* hn     = h + (size_t)LSEQ * DM;      // L*DM
    float* xz     = hn + (size_t)LSEQ * DM;     // L*2048 (aliased: fc1/out_proj partials, amx)
    float* xc     = xz + (size_t)LSEQ * 2 * DI; // L*DI
    float* dbc    = xc + (size_t)LSEQ * DI;     // L*64
    float* delta  = dbc + (size_t)LSEQ * 64;    // L*DI
    float* yb     = delta + (size_t)LSEQ * DI;  // L*DI (aliased: x_proj partials)
    float* hf     = yb + (size_t)LSEQ * DI;     // L*DM
    float* scores = hf + (size_t)LSEQ * DM;     // L
    float* wts    = scores + LSEQ;              // L
    float* pooled = wts + LSEQ;                 // DM
    float* c1     = pooled + DM;                // 256*16
    float* c2     = c1 + 256 * 16;              // 128*256
    float* c3     = c2 + 128 * 256;             // 64*1024
    float* c4     = c3 + 64 * 1024;             // 32*4096
    float* aprod  = c4 + 32 * 4096;             // NC*NST*DI (32*16*1024)
    float* hfin   = aprod + (size_t)NC * NST * DI;
    float* carry  = hfin + (size_t)NC * NST * DI;
    float* part   = carry + (size_t)NC * NST * DI;  // 16*DM (pooled partials)
    float* partk  = yb;                          // alias: x_proj split-K partials
    float* skpart = xz;                          // alias: fc1/out_proj 8 partials
    float* amx    = xz;                          // alias: attn pre-act [L,128]

    // fc1 (split-K=8 -> 1024 blocks) -> fused reduce+gelu+pos+rms
    gemm_w<<<dim3(DM / 64, LSEQ / 128, 8), 128, 0, stream>>>(x, 1024, Wfc1, DM, skpart, DM, 1024);
    fc1_fin<<<LSEQ, 256, 0, stream>>>(skpart, bfc1, coords, Wpos, bpos, rms_w, h, hn);

    for (int l = 0; l < 2; ++l) {
        // in_proj: gemm_s direct (1024 blocks, 2 waves) — no reduce pass
        gemm_s<<<dim3(2 * DI / 64, LSEQ / 64, 1), 128, 0, stream>>>(
            hn, DM, in_w + (size_t)l * DM * 2 * DI, 2 * DI, xz, 2 * DI, DM);
        conv_silu_k<<<LSEQ * DI / 256, 256, 0, stream>>>(
            xz, conv_w + (size_t)l * DI * 4, conv_b + (size_t)l * DI, xc);
        xproj_splitk<<<dim3(8, LSEQ / 64), 256, 0, stream>>>(
            xc, x_w + (size_t)l * DI * 64, partk);
        xproj_reduce<<<LSEQ * 64 / 256, 256, 0, stream>>>(partk, dbc);
        dtproj_k<<<dim3(DI / 64, LSEQ / 64), 256, 0, stream>>>(
            dbc, dt_w + (size_t)l * 32 * DI, dt_b + (size_t)l * DI, delta);
        scan_p1<<<dim3(DI / 128, NC), 128, 0, stream>>>(
            delta, xc, dbc, A_log + (size_t)l * DI * NST, aprod, hfin);
        scan_carry<<<NST * DI / 256, 256, 0, stream>>>(aprod, hfin, carry);
        scan_p2<<<dim3(DI / 128, NC), 128, 0, stream>>>(
            delta, xc, dbc, xz, A_log + (size_t)l * DI * NST, Dp + (size_t)l * DI,
            carry, yb);
        // out_proj split-K=8 -> fused residual-add + next norm
        gemm_w<<<dim3(DM / 64, LSEQ / 128, 8), 128, 0, stream>>>(
            yb, DI, out_w + (size_t)l * DI * DM, DM, skpart, DM, 1024);
        if (l == 0)
            skadd_norm<<<LSEQ, 256, 0, stream>>>(skpart, h, rms_w + DM, nullptr, hn, 0);
        else
            skadd_norm<<<LSEQ, 256, 0, stream>>>(skpart, h, ln_w, ln_b, hf, 1);
    }

    gemm64<<<dim3(2, LSEQ / 64), 256, 0, stream>>>(hf, DM, Wa1, 128, amx, 128, DM, 0);
    attn_fin<<<LSEQ / 4, 256, 0, stream>>>(amx, ba1, Wa2, ba2, scores);
    softmax_k<<<1, 1024, 0, stream>>>(scores, wts);
    pooled_p1<<<dim3(2, 16), 256, 0, stream>>>(wts, hf, part);
    pooled_p2<<<2, 256, 0, stream>>>(part, pooled);

    ct1_fast<<<256, 256, 0, stream>>>(pooled, ct1w, ct1b, c1);
    ct2_fast<<<dim3(16, 128), 256, 0, stream>>>(c1, ct2w, ct2b, c2);
    ctup_fast<<<dim3(32, 64), 256, 0, stream>>>(c2, ct3w, ct3b, c3, 128, 64, 16, 4, 1);
    ctup_fast<<<dim3(64, 32), 256, 0, stream>>>(c3, ct4w, ct4b, c4, 64, 32, 32, 5, 1);
    ctup_fast<<<dim3(128, 11), 256, 0, stream>>>(c4, ct5w, ct5b, (float*)d_out, 32, 11, 64, 6, 0);
}

// Round 13
// 667.860 us; speedup vs baseline: 1.0898x; 1.0898x over previous
//
#include <hip/hip_runtime.h>
#include <math.h>

#define LSEQ 2048
#define DM 512
#define DI 1024
#define NST 16
#define CHUNK 32
#define NC (LSEQ / CHUNK)

__device__ __forceinline__ float siluf(float v) { return v / (1.f + expf(-v)); }

// ---------------- gemm_s: 64x64 tile, 128 threads (2 waves), 4x8 micro, BK=16 ---
__global__ __launch_bounds__(128) void gemm_s(
    const float* __restrict__ A, int lda,
    const float* __restrict__ B, int ldb,
    float* __restrict__ out, int ldc, int Ktot)
{
    __shared__ float As[16][68];
    __shared__ float Bs[16][68];
    const int tid = threadIdx.x;
    const int tx = tid & 7, ty = tid >> 3;
    const int n0 = blockIdx.x << 6, m0 = blockIdx.y << 6;
    const int z = blockIdx.z, nz = gridDim.z;
    const int Kz = Ktot / nz, kb = z * Kz;
    const int arow = tid >> 1, ak = (tid & 1) << 3;
    const int bkr = tid >> 3, bcol = (tid & 7) << 3;
    const float* Ap = A + (size_t)(m0 + arow) * lda + kb + ak;
    const float* Bp = B + (size_t)(kb + bkr) * ldb + n0 + bcol;
    float acc[4][8] = {};
    float4 a0 = *(const float4*)(Ap);
    float4 a1 = *(const float4*)(Ap + 4);
    float4 b0 = *(const float4*)(Bp);
    float4 b1 = *(const float4*)(Bp + 4);
    for (int k0 = 0; k0 < Kz; k0 += 16) {
        As[ak + 0][arow] = a0.x; As[ak + 1][arow] = a0.y;
        As[ak + 2][arow] = a0.z; As[ak + 3][arow] = a0.w;
        As[ak + 4][arow] = a1.x; As[ak + 5][arow] = a1.y;
        As[ak + 6][arow] = a1.z; As[ak + 7][arow] = a1.w;
        *(float4*)&Bs[bkr][bcol] = b0;
        *(float4*)&Bs[bkr][bcol + 4] = b1;
        __syncthreads();
        if (k0 + 16 < Kz) {
            a0 = *(const float4*)(Ap + k0 + 16);
            a1 = *(const float4*)(Ap + k0 + 20);
            b0 = *(const float4*)(Bp + (size_t)(k0 + 16) * ldb);
            b1 = *(const float4*)(Bp + (size_t)(k0 + 16) * ldb + 4);
        }
#pragma unroll
        for (int kk = 0; kk < 16; ++kk) {
            float4 a = *(const float4*)&As[kk][ty << 2];
            float4 bb0 = *(const float4*)&Bs[kk][tx << 3];
            float4 bb1 = *(const float4*)&Bs[kk][(tx << 3) + 4];
            float av[4] = {a.x, a.y, a.z, a.w};
            float bv[8] = {bb0.x, bb0.y, bb0.z, bb0.w, bb1.x, bb1.y, bb1.z, bb1.w};
#pragma unroll
            for (int i = 0; i < 4; ++i)
#pragma unroll
                for (int j = 0; j < 8; ++j)
                    acc[i][j] = fmaf(av[i], bv[j], acc[i][j]);
        }
        __syncthreads();
    }
    const int Mtot = gridDim.y << 6;
    float* op = out + (size_t)z * Mtot * ldc;
#pragma unroll
    for (int i = 0; i < 4; ++i) {
        float* Cp = op + (size_t)(m0 + (ty << 2) + i) * ldc + n0 + (tx << 3);
        *(float4*)Cp = make_float4(acc[i][0], acc[i][1], acc[i][2], acc[i][3]);
        *(float4*)(Cp + 4) = make_float4(acc[i][4], acc[i][5], acc[i][6], acc[i][7]);
    }
}

// ---------------- gemm_w: 128(M)x64(N) tile, 128 thr, 8x8 micro, BK=16 ----------
__global__ __launch_bounds__(128) void gemm_w(
    const float* __restrict__ A, int lda,
    const float* __restrict__ B, int ldb,
    float* __restrict__ out, int ldc, int Ktot)
{
    __shared__ float As[16][192];
    __shared__ float Bs[16][68];
    const int tid = threadIdx.x;
    const int tx = tid & 7, ty = tid >> 3;
    const int n0 = blockIdx.x << 6, m0 = blockIdx.y << 7;
    const int z = blockIdx.z, nz = gridDim.z;
    const int Kz = Ktot / nz, kb = z * Kz;
    const int apos = ((tid >> 3) * 12) + (tid & 7);
    const int bkr = tid >> 3, bcol = (tid & 7) << 3;
    const float* Ap = A + (size_t)(m0 + tid) * lda + kb;
    const float* Bp = B + (size_t)(kb + bkr) * ldb + n0 + bcol;
    float acc[8][8] = {};
    float4 a0 = *(const float4*)(Ap + 0);
    float4 a1 = *(const float4*)(Ap + 4);
    float4 a2 = *(const float4*)(Ap + 8);
    float4 a3 = *(const float4*)(Ap + 12);
    float4 b0 = *(const float4*)(Bp + 0);
    float4 b1 = *(const float4*)(Bp + 4);
    for (int k0 = 0; k0 < Kz; k0 += 16) {
        As[0][apos] = a0.x;  As[1][apos] = a0.y;  As[2][apos] = a0.z;  As[3][apos] = a0.w;
        As[4][apos] = a1.x;  As[5][apos] = a1.y;  As[6][apos] = a1.z;  As[7][apos] = a1.w;
        As[8][apos] = a2.x;  As[9][apos] = a2.y;  As[10][apos] = a2.z; As[11][apos] = a2.w;
        As[12][apos] = a3.x; As[13][apos] = a3.y; As[14][apos] = a3.z; As[15][apos] = a3.w;
        *(float4*)&Bs[bkr][bcol] = b0;
        *(float4*)&Bs[bkr][bcol + 4] = b1;
        __syncthreads();
        if (k0 + 16 < Kz) {
            a0 = *(const float4*)(Ap + k0 + 16);
            a1 = *(const float4*)(Ap + k0 + 20);
            a2 = *(const float4*)(Ap + k0 + 24);
            a3 = *(const float4*)(Ap + k0 + 28);
            b0 = *(const float4*)(Bp + (size_t)(k0 + 16) * ldb);
            b1 = *(const float4*)(Bp + (size_t)(k0 + 16) * ldb + 4);
        }
#pragma unroll
        for (int kk = 0; kk < 16; ++kk) {
            float4 av0 = *(const float4*)&As[kk][ty * 12];
            float4 av1 = *(const float4*)&As[kk][ty * 12 + 4];
            float4 bv0 = *(const float4*)&Bs[kk][tx << 3];
            float4 bv1 = *(const float4*)&Bs[kk][(tx << 3) + 4];
            float a8[8] = {av0.x, av0.y, av0.z, av0.w, av1.x, av1.y, av1.z, av1.w};
            float b8[8] = {bv0.x, bv0.y, bv0.z, bv0.w, bv1.x, bv1.y, bv1.z, bv1.w};
#pragma unroll
            for (int i = 0; i < 8; ++i)
#pragma unroll
                for (int j = 0; j < 8; ++j)
                    acc[i][j] = fmaf(a8[i], b8[j], acc[i][j]);
        }
        __syncthreads();
    }
    const int Mtot = gridDim.y << 7;
    float* op = out + (size_t)z * Mtot * ldc;
#pragma unroll
    for (int i = 0; i < 8; ++i) {
        float* Cp = op + (size_t)(m0 + (ty << 3) + i) * ldc + n0 + (tx << 3);
        *(float4*)Cp = make_float4(acc[i][0], acc[i][1], acc[i][2], acc[i][3]);
        *(float4*)(Cp + 4) = make_float4(acc[i][4], acc[i][5], acc[i][6], acc[i][7]);
    }
}

// ---------------- dt_proj fused: delta = softplus(dbc[:, :32] @ dt_w + dt_b) ----
__global__ __launch_bounds__(256) void dtproj_k(
    const float* __restrict__ A, const float* __restrict__ B,
    const float* __restrict__ dtb, float* __restrict__ delta)
{
    __shared__ float As[16][68];
    __shared__ float Bs[16][68];
    const int tid = threadIdx.x;
    const int tx = tid & 15, ty = tid >> 4;
    const int m0 = blockIdx.y << 6, n0 = blockIdx.x << 6;
    const int arow = tid >> 2, akk = (tid & 3) << 2;
    const int bkr = tid >> 4, bnn = (tid & 15) << 2;
    const float* Ap = A + (size_t)(m0 + arow) * 64 + akk;
    const float* Bp = B + (size_t)bkr * DI + n0 + bnn;
    float acc[4][4] = {};
    for (int k0 = 0; k0 < 32; k0 += 16) {
        float4 av = *(const float4*)(Ap + k0);
        float4 bv = *(const float4*)(Bp + (size_t)k0 * DI);
        As[akk + 0][arow] = av.x;
        As[akk + 1][arow] = av.y;
        As[akk + 2][arow] = av.z;
        As[akk + 3][arow] = av.w;
        *(float4*)&Bs[bkr][bnn] = bv;
        __syncthreads();
#pragma unroll
        for (int kk = 0; kk < 16; ++kk) {
            float4 a = *(const float4*)&As[kk][ty << 2];
            float4 b = *(const float4*)&Bs[kk][tx << 2];
#pragma unroll
            for (int i = 0; i < 4; ++i) {
                float ai = (i == 0) ? a.x : (i == 1) ? a.y : (i == 2) ? a.z : a.w;
                acc[i][0] = fmaf(ai, b.x, acc[i][0]);
                acc[i][1] = fmaf(ai, b.y, acc[i][1]);
                acc[i][2] = fmaf(ai, b.z, acc[i][2]);
                acc[i][3] = fmaf(ai, b.w, acc[i][3]);
            }
        }
        __syncthreads();
    }
    const int col = n0 + (tx << 2);
    float4 bb = *(const float4*)&dtb[col];
    float bias[4] = {bb.x, bb.y, bb.z, bb.w};
#pragma unroll
    for (int i = 0; i < 4; ++i) {
        float* Cp = delta + (size_t)(m0 + (ty << 2) + i) * DI + col;
#pragma unroll
        for (int j = 0; j < 4; ++j) {
            float v = acc[i][j] + bias[j];
            Cp[j] = fmaxf(v, 0.f) + log1pf(expf(-fabsf(v)));
        }
    }
}

// ---------------- generic fp32 GEMM: 64x64 tile, 4x4 micro, BK=16 ---------------
__global__ __launch_bounds__(256) void gemm64(
    const float* __restrict__ A, int lda,
    const float* __restrict__ B, int ldb,
    float* __restrict__ C, int ldc,
    int K, int accum)
{
    __shared__ float As[16][68];
    __shared__ float Bs[16][68];
    const int tid = threadIdx.x;
    const int tx = tid & 15, ty = tid >> 4;
    const int m0 = blockIdx.y << 6, n0 = blockIdx.x << 6;
    const int arow = tid >> 2, akk = (tid & 3) << 2;
    const int bkr = tid >> 4, bnn = (tid & 15) << 2;
    const float* Ap = A + (size_t)(m0 + arow) * lda + akk;
    const float* Bp = B + (size_t)bkr * ldb + n0 + bnn;
    float acc[4][4] = {};
    for (int k0 = 0; k0 < K; k0 += 16) {
        float4 av = *(const float4*)(Ap + k0);
        float4 bv = *(const float4*)(Bp + (size_t)k0 * ldb);
        As[akk + 0][arow] = av.x;
        As[akk + 1][arow] = av.y;
        As[akk + 2][arow] = av.z;
        As[akk + 3][arow] = av.w;
        *(float4*)&Bs[bkr][bnn] = bv;
        __syncthreads();
#pragma unroll
        for (int kk = 0; kk < 16; ++kk) {
            float4 a = *(const float4*)&As[kk][ty << 2];
            float4 b = *(const float4*)&Bs[kk][tx << 2];
            acc[0][0] = fmaf(a.x, b.x, acc[0][0]);
            acc[0][1] = fmaf(a.x, b.y, acc[0][1]);
            acc[0][2] = fmaf(a.x, b.z, acc[0][2]);
            acc[0][3] = fmaf(a.x, b.w, acc[0][3]);
            acc[1][0] = fmaf(a.y, b.x, acc[1][0]);
            acc[1][1] = fmaf(a.y, b.y, acc[1][1]);
            acc[1][2] = fmaf(a.y, b.z, acc[1][2]);
            acc[1][3] = fmaf(a.y, b.w, acc[1][3]);
            acc[2][0] = fmaf(a.z, b.x, acc[2][0]);
            acc[2][1] = fmaf(a.z, b.y, acc[2][1]);
            acc[2][2] = fmaf(a.z, b.z, acc[2][2]);
            acc[2][3] = fmaf(a.z, b.w, acc[2][3]);
            acc[3][0] = fmaf(a.w, b.x, acc[3][0]);
            acc[3][1] = fmaf(a.w, b.y, acc[3][1]);
            acc[3][2] = fmaf(a.w, b.z, acc[3][2]);
            acc[3][3] = fmaf(a.w, b.w, acc[3][3]);
        }
        __syncthreads();
    }
#pragma unroll
    for (int i = 0; i < 4; ++i) {
        float* Cp = C + (size_t)(m0 + (ty << 2) + i) * ldc + n0 + (tx << 2);
        if (accum) {
            Cp[0] += acc[i][0]; Cp[1] += acc[i][1]; Cp[2] += acc[i][2]; Cp[3] += acc[i][3];
        } else {
            Cp[0] = acc[i][0]; Cp[1] = acc[i][1]; Cp[2] = acc[i][2]; Cp[3] = acc[i][3];
        }
    }
}

// ---------------- x_proj split-K: [2048,1024]@[1024,64] -> partials -------------
__global__ __launch_bounds__(256) void xproj_splitk(
    const float* __restrict__ A, const float* __restrict__ B,
    float* __restrict__ part)
{
    __shared__ float As[16][68];
    __shared__ float Bs[16][68];
    const int tid = threadIdx.x;
    const int tx = tid & 15, ty = tid >> 4;
    const int ks = blockIdx.x;
    const int m0 = blockIdx.y << 6;
    const int arow = tid >> 2, ak = (tid & 3) << 2;
    const int bkr = tid >> 4, bcol = (tid & 15) << 2;
    const int kbase = ks << 7;
    const float* Ap = A + (size_t)(m0 + arow) * DI + kbase + ak;
    const float* Bp = B + (size_t)(kbase + bkr) * 64 + bcol;
    float acc[4][4] = {};
    for (int k0 = 0; k0 < 128; k0 += 16) {
        float4 av = *(const float4*)(Ap + k0);
        float4 bv = *(const float4*)(Bp + k0 * 64);
        As[ak + 0][arow] = av.x;
        As[ak + 1][arow] = av.y;
        As[ak + 2][arow] = av.z;
        As[ak + 3][arow] = av.w;
        *(float4*)&Bs[bkr][bcol] = bv;
        __syncthreads();
#pragma unroll
        for (int kk = 0; kk < 16; ++kk) {
            float4 a = *(const float4*)&As[kk][ty << 2];
            float4 b = *(const float4*)&Bs[kk][tx << 2];
            acc[0][0] = fmaf(a.x, b.x, acc[0][0]);
            acc[0][1] = fmaf(a.x, b.y, acc[0][1]);
            acc[0][2] = fmaf(a.x, b.z, acc[0][2]);
            acc[0][3] = fmaf(a.x, b.w, acc[0][3]);
            acc[1][0] = fmaf(a.y, b.x, acc[1][0]);
            acc[1][1] = fmaf(a.y, b.y, acc[1][1]);
            acc[1][2] = fmaf(a.y, b.z, acc[1][2]);
            acc[1][3] = fmaf(a.y, b.w, acc[1][3]);
            acc[2][0] = fmaf(a.z, b.x, acc[2][0]);
            acc[2][1] = fmaf(a.z, b.y, acc[2][1]);
            acc[2][2] = fmaf(a.z, b.z, acc[2][2]);
            acc[2][3] = fmaf(a.z, b.w, acc[2][3]);
            acc[3][0] = fmaf(a.w, b.x, acc[3][0]);
            acc[3][1] = fmaf(a.w, b.y, acc[3][1]);
            acc[3][2] = fmaf(a.w, b.z, acc[3][2]);
            acc[3][3] = fmaf(a.w, b.w, acc[3][3]);
        }
        __syncthreads();
    }
#pragma unroll
    for (int i = 0; i < 4; ++i) {
        float* Cp = part + ((size_t)ks * LSEQ + m0 + (ty << 2) + i) * 64 + (tx << 2);
        Cp[0] = acc[i][0]; Cp[1] = acc[i][1]; Cp[2] = acc[i][2]; Cp[3] = acc[i][3];
    }
}

__global__ __launch_bounds__(256) void xproj_reduce(
    const float* __restrict__ part, float* __restrict__ dbc)
{
    const int idx = blockIdx.x * 256 + threadIdx.x;   // LSEQ*64
    float s = 0.f;
#pragma unroll
    for (int ks = 0; ks < 8; ++ks) s += part[(size_t)ks * LSEQ * 64 + idx];
    dbc[idx] = s;
}

// ---------------- fc1_fin: sk-reduce(8) + bias + GELU + pos + RMS ---------------
__global__ __launch_bounds__(256) void fc1_fin(
    const float* __restrict__ part,
    const float* __restrict__ bfc1, const float* __restrict__ coords,
    const float* __restrict__ Wpos, const float* __restrict__ bpos,
    const float* __restrict__ rw,
    float* __restrict__ h, float* __restrict__ hn)
{
    const int t = blockIdx.x, tid = threadIdx.x;
    const size_t base = (size_t)t * DM;
    float va = 0.f, vb = 0.f;
#pragma unroll
    for (int z = 0; z < 8; ++z) {
        va += part[(size_t)z * LSEQ * DM + base + tid];
        vb += part[(size_t)z * LSEQ * DM + base + 256 + tid];
    }
    const float cx = coords[2 * t], cy = coords[2 * t + 1];
    va += bfc1[tid];
    vb += bfc1[256 + tid];
    float ga = 0.5f * va * (1.f + erff(va * 0.70710678118654752f));
    float gb = 0.5f * vb * (1.f + erff(vb * 0.70710678118654752f));
    ga += cx * Wpos[tid] + cy * Wpos[DM + tid] + bpos[tid];
    gb += cx * Wpos[256 + tid] + cy * Wpos[DM + 256 + tid] + bpos[256 + tid];
    h[base + tid] = ga;
    h[base + 256 + tid] = gb;
    float ss = ga * ga + gb * gb;
#pragma unroll
    for (int off = 1; off < 64; off <<= 1) ss += __shfl_xor(ss, off);
    __shared__ float red[4];
    if ((tid & 63) == 0) red[tid >> 6] = ss;
    __syncthreads();
    float inv = rsqrtf((red[0] + red[1] + red[2] + red[3]) * (1.f / DM) + 1e-5f);
    hn[base + tid] = ga * inv * rw[tid];
    hn[base + 256 + tid] = gb * inv * rw[256 + tid];
}

// ---------------- skadd_norm: h += sum_z(8) part[z]; then RMS or LN -------------
__global__ __launch_bounds__(256) void skadd_norm(
    const float* __restrict__ part, float* __restrict__ h,
    const float* __restrict__ w1, const float* __restrict__ b1,
    float* __restrict__ outb, int mode)
{
    const int t = blockIdx.x, tid = threadIdx.x;
    const size_t base = (size_t)t * DM;
    float va = h[base + tid], vb = h[base + 256 + tid];
#pragma unroll
    for (int z = 0; z < 8; ++z) {
        va += part[(size_t)z * LSEQ * DM + base + tid];
        vb += part[(size_t)z * LSEQ * DM + base + 256 + tid];
    }
    h[base + tid] = va;
    h[base + 256 + tid] = vb;
    __shared__ float red1[4], red2[4];
    if (mode == 0) {
        float ss = va * va + vb * vb;
#pragma unroll
        for (int off = 1; off < 64; off <<= 1) ss += __shfl_xor(ss, off);
        if ((tid & 63) == 0) red1[tid >> 6] = ss;
        __syncthreads();
        float inv = rsqrtf((red1[0] + red1[1] + red1[2] + red1[3]) * (1.f / DM) + 1e-5f);
        outb[base + tid] = va * inv * w1[tid];
        outb[base + 256 + tid] = vb * inv * w1[256 + tid];
    } else {
        float s = va + vb;
#pragma unroll
        for (int off = 1; off < 64; off <<= 1) s += __shfl_xor(s, off);
        if ((tid & 63) == 0) red1[tid >> 6] = s;
        __syncthreads();
        float mean = (red1[0] + red1[1] + red1[2] + red1[3]) * (1.f / DM);
        float da = va - mean, db = vb - mean;
        float vs = da * da + db * db;
#pragma unroll
        for (int off = 1; off < 64; off <<= 1) vs += __shfl_xor(vs, off);
        if ((tid & 63) == 0) red2[tid >> 6] = vs;
        __syncthreads();
        float inv = rsqrtf((red2[0] + red2[1] + red2[2] + red2[3]) * (1.f / DM) + 1e-5f);
        outb[base + tid] = da * inv * w1[tid] + b1[tid];
        outb[base + 256 + tid] = db * inv * w1[256 + tid] + b1[256 + tid];
    }
}

// ---------------- causal depthwise conv (k=4) + SiLU, float4 --------------------
__global__ __launch_bounds__(256) void conv_silu_k(
    const float* __restrict__ xz, const float* __restrict__ cw,
    const float* __restrict__ cb, float* __restrict__ xc)
{
    int idx = blockIdx.x * 256 + threadIdx.x;   // L*DI/4
    int t = idx >> 8, c4 = (idx & 255) << 2;    // 256 float4 per row
    float4 w0 = *(const float4*)&cw[c4 * 4];
    float4 w1 = *(const float4*)&cw[c4 * 4 + 4];
    float4 w2 = *(const float4*)&cw[c4 * 4 + 8];
    float4 w3 = *(const float4*)&cw[c4 * 4 + 12];
    float4 bb = *(const float4*)&cb[c4];
    // weights laid [c][4]; per channel j: taps cw[(c4+j)*4 + k]
    float4 s = bb;
    float4 v;
    if (t >= 3) {
        v = *(const float4*)&xz[(size_t)(t - 3) * 2048 + c4];
        s.x = fmaf(v.x, w0.x, s.x); s.y = fmaf(v.y, w1.x, s.y);
        s.z = fmaf(v.z, w2.x, s.z); s.w = fmaf(v.w, w3.x, s.w);
    }
    if (t >= 2) {
        v = *(const float4*)&xz[(size_t)(t - 2) * 2048 + c4];
        s.x = fmaf(v.x, w0.y, s.x); s.y = fmaf(v.y, w1.y, s.y);
        s.z = fmaf(v.z, w2.y, s.z); s.w = fmaf(v.w, w3.y, s.w);
    }
    if (t >= 1) {
        v = *(const float4*)&xz[(size_t)(t - 1) * 2048 + c4];
        s.x = fmaf(v.x, w0.z, s.x); s.y = fmaf(v.y, w1.z, s.y);
        s.z = fmaf(v.z, w2.z, s.z); s.w = fmaf(v.w, w3.z, s.w);
    }
    v = *(const float4*)&xz[(size_t)t * 2048 + c4];
    s.x = fmaf(v.x, w0.w, s.x); s.y = fmaf(v.y, w1.w, s.y);
    s.z = fmaf(v.z, w2.w, s.z); s.w = fmaf(v.w, w3.w, s.w);
    float4 o;
    o.x = siluf(s.x); o.y = siluf(s.y); o.z = siluf(s.z); o.w = siluf(s.w);
    *(float4*)&xc[(size_t)t * DI + c4] = o;
}

// ===================== state-in-register chunked selective scan =================
__global__ __launch_bounds__(128) void scan_p1(
    const float* __restrict__ delta, const float* __restrict__ xc,
    const float* __restrict__ dbc, const float* __restrict__ alog,
    float* __restrict__ aprod, float* __restrict__ hfin)
{
    __shared__ float sB[CHUNK][16];
    const int tid = threadIdx.x;
    const int d = (blockIdx.x << 7) + tid;
    const int c = blockIdx.y;
    const int t0 = c * CHUNK;
    for (int i = tid; i < CHUNK * 16; i += 128)
        sB[i >> 4][i & 15] = dbc[(size_t)(t0 + (i >> 4)) * 64 + 32 + (i & 15)];
    float An[NST];
#pragma unroll
    for (int n = 0; n < NST; ++n) An[n] = -expf(alog[d * NST + n]);
    __syncthreads();
    float h[NST] = {}, ap[NST];
#pragma unroll
    for (int n = 0; n < NST; ++n) ap[n] = 1.f;
    float dl = delta[(size_t)t0 * DI + d];
    float xv = xc[(size_t)t0 * DI + d];
    for (int i = 0; i < CHUNK; ++i) {
        float dln = 0.f, xvn = 0.f;
        if (i + 1 < CHUNK) {
            dln = delta[(size_t)(t0 + i + 1) * DI + d];
            xvn = xc[(size_t)(t0 + i + 1) * DI + d];
        }
        const float dlx = dl * xv;
        float4 b0 = *(const float4*)&sB[i][0];
        float4 b1 = *(const float4*)&sB[i][4];
        float4 b2 = *(const float4*)&sB[i][8];
        float4 b3 = *(const float4*)&sB[i][12];
        float Bv[NST] = {b0.x, b0.y, b0.z, b0.w, b1.x, b1.y, b1.z, b1.w,
                         b2.x, b2.y, b2.z, b2.w, b3.x, b3.y, b3.z, b3.w};
#pragma unroll
        for (int n = 0; n < NST; ++n) {
            float a = expf(dl * An[n]);
            h[n] = fmaf(a, h[n], dlx * Bv[n]);
            ap[n] *= a;
        }
        dl = dln; xv = xvn;
    }
#pragma unroll
    for (int n = 0; n < NST; ++n) {
        aprod[((size_t)c * NST + n) * DI + d] = ap[n];
        hfin[((size_t)c * NST + n) * DI + d] = h[n];
    }
}

__global__ __launch_bounds__(256) void scan_carry(
    const float* __restrict__ aprod, const float* __restrict__ hfin,
    float* __restrict__ carry)
{
    const int idx = blockIdx.x * 256 + threadIdx.x;   // NST*DI = 16384
    float h = 0.f;
    carry[idx] = 0.f;
    for (int c = 0; c < NC - 1; ++c) {
        h = fmaf(aprod[(size_t)c * NST * DI + idx], h, hfin[(size_t)c * NST * DI + idx]);
        carry[(size_t)(c + 1) * NST * DI + idx] = h;
    }
}

__global__ __launch_bounds__(128) void scan_p2(
    const float* __restrict__ delta, const float* __restrict__ xc,
    const float* __restrict__ dbc, const float* __restrict__ xz,
    const float* __restrict__ alog, const float* __restrict__ Dp,
    const float* __restrict__ carry, float* __restrict__ y)
{
    __shared__ float sB[CHUNK][16];
    __shared__ float sC[CHUNK][16];
    const int tid = threadIdx.x;
    const int d = (blockIdx.x << 7) + tid;
    const int c = blockIdx.y;
    const int t0 = c * CHUNK;
    for (int i = tid; i < CHUNK * 16; i += 128) {
        sB[i >> 4][i & 15] = dbc[(size_t)(t0 + (i >> 4)) * 64 + 32 + (i & 15)];
        sC[i >> 4][i & 15] = dbc[(size_t)(t0 + (i >> 4)) * 64 + 48 + (i & 15)];
    }
    float An[NST];
#pragma unroll
    for (int n = 0; n < NST; ++n) An[n] = -expf(alog[d * NST + n]);
    const float Dd = Dp[d];
    float h[NST];
#pragma unroll
    for (int n = 0; n < NST; ++n) h[n] = carry[((size_t)c * NST + n) * DI + d];
    __syncthreads();
    float dl = delta[(size_t)t0 * DI + d];
    float xv = xc[(size_t)t0 * DI + d];
    float zz = xz[(size_t)t0 * 2048 + 1024 + d];
    for (int i = 0; i < CHUNK; ++i) {
        float dln = 0.f, xvn = 0.f, zzn = 0.f;
        if (i + 1 < CHUNK) {
            dln = delta[(size_t)(t0 + i + 1) * DI + d];
            xvn = xc[(size_t)(t0 + i + 1) * DI + d];
            zzn = xz[(size_t)(t0 + i + 1) * 2048 + 1024 + d];
        }
        const float dlx = dl * xv;
        float4 b0 = *(const float4*)&sB[i][0];
        float4 b1 = *(const float4*)&sB[i][4];
        float4 b2 = *(const float4*)&sB[i][8];
        float4 b3 = *(const float4*)&sB[i][12];
        float4 c0 = *(const float4*)&sC[i][0];
        float4 c1 = *(const float4*)&sC[i][4];
        float4 c2 = *(const float4*)&sC[i][8];
        float4 c3 = *(const float4*)&sC[i][12];
        float Bv[NST] = {b0.x, b0.y, b0.z, b0.w, b1.x, b1.y, b1.z, b1.w,
                         b2.x, b2.y, b2.z, b2.w, b3.x, b3.y, b3.z, b3.w};
        float Cv[NST] = {c0.x, c0.y, c0.z, c0.w, c1.x, c1.y, c1.z, c1.w,
                         c2.x, c2.y, c2.z, c2.w, c3.x, c3.y, c3.z, c3.w};
        float p = 0.f;
#pragma unroll
        for (int n = 0; n < NST; ++n) {
            float a = expf(dl * An[n]);
            h[n] = fmaf(a, h[n], dlx * Bv[n]);
            p = fmaf(h[n], Cv[n], p);
        }
        y[(size_t)(t0 + i) * DI + d] = (p + xv * Dd) * siluf(zz);
        dl = dln; xv = xvn; zz = zzn;
    }
}

// ---------------- attn epilogue: scores = tanh(amx+ba1)@Wa2 + ba2 ---------------
__global__ __launch_bounds__(256) void attn_fin(
    const float* __restrict__ amx, const float* __restrict__ ba1,
    const float* __restrict__ Wa2, const float* __restrict__ ba2,
    float* __restrict__ scores)
{
    const int tid = threadIdx.x;
    const int row = blockIdx.x * 4 + (tid >> 6);
    const int lane = tid & 63;
    float v = tanhf(amx[(size_t)row * 128 + lane] + ba1[lane]) * Wa2[lane]
            + tanhf(amx[(size_t)row * 128 + 64 + lane] + ba1[64 + lane]) * Wa2[64 + lane];
#pragma unroll
    for (int off = 1; off < 64; off <<= 1) v += __shfl_xor(v, off);
    if (lane == 0) scores[row] = v + ba2[0];
}

// ---------------- softmax over 2048 scores (one block) --------------------------
__global__ __launch_bounds__(1024) void softmax_k(
    const float* __restrict__ s, float* __restrict__ w)
{
    const int tid = threadIdx.x;
    __shared__ float red[16];
    float m = fmaxf(s[tid], s[tid + 1024]);
#pragma unroll
    for (int off = 1; off < 64; off <<= 1) m = fmaxf(m, __shfl_xor(m, off));
    if ((tid & 63) == 0) red[tid >> 6] = m;
    __syncthreads();
    if (tid < 64) {
        float mm = (tid < 16) ? red[tid] : -1e30f;
#pragma unroll
        for (int off = 1; off < 16; off <<= 1) mm = fmaxf(mm, __shfl_xor(mm, off));
        if (tid == 0) red[0] = mm;
    }
    __syncthreads();
    const float gm = red[0];
    __syncthreads();
    float e0 = expf(s[tid] - gm), e1 = expf(s[tid + 1024] - gm);
    float sum = e0 + e1;
#pragma unroll
    for (int off = 1; off < 64; off <<= 1) sum += __shfl_xor(sum, off);
    __shared__ float red2[16];
    if ((tid & 63) == 0) red2[tid >> 6] = sum;
    __syncthreads();
    if (tid < 64) {
        float ss = (tid < 16) ? red2[tid] : 0.f;
#pragma unroll
        for (int off = 1; off < 16; off <<= 1) ss += __shfl_xor(ss, off);
        if (tid == 0) red2[0] = ss;
    }
    __syncthreads();
    float inv = 1.f / red2[0];
    w[tid] = e0 * inv;
    w[tid + 1024] = e1 * inv;
}

// ---------------- pooled: two-stage  part[tc,j] then sum ------------------------
__global__ __launch_bounds__(256) void pooled_p1(
    const float* __restrict__ wts, const float* __restrict__ hf, float* __restrict__ part)
{
    const int j = blockIdx.x * 256 + threadIdx.x;   // 0..511
    const int tc = blockIdx.y;                       // 16 chunks of 128
    float acc = 0.f;
    const int t0 = tc * 128;
    for (int t = t0; t < t0 + 128; ++t) acc = fmaf(wts[t], hf[(size_t)t * DM + j], acc);
    part[(size_t)tc * DM + j] = acc;
}

__global__ __launch_bounds__(256) void pooled_p2(
    const float* __restrict__ part, float* __restrict__ pooled)
{
    const int j = blockIdx.x * 256 + threadIdx.x;
    float acc = 0.f;
#pragma unroll
    for (int tc = 0; tc < 16; ++tc) acc += part[(size_t)tc * DM + j];
    pooled[j] = acc;
}

// ---------------- ct1: ConvT 1x1->4x4 (s=1,p=0), 512->256, relu -----------------
__global__ __launch_bounds__(256) void ct1_fast(
    const float* __restrict__ feat, const float* __restrict__ w,
    const float* __restrict__ b, float* __restrict__ out)
{
    __shared__ float sf[512];
    __shared__ float sRed[256];
    const int o = blockIdx.x, tid = threadIdx.x;
    sf[tid] = feat[tid];
    sf[tid + 256] = feat[tid + 256];
    __syncthreads();
    const int p = tid & 15, g = tid >> 4;
    float acc = 0.f;
#pragma unroll 8
    for (int ci = g * 32; ci < g * 32 + 32; ++ci)
        acc = fmaf(sf[ci], w[ci * 4096 + (o << 4) + p], acc);
    sRed[tid] = acc;
    __syncthreads();
    if (g == 0) {
        float s = b[o];
#pragma unroll
        for (int gg = 0; gg < 16; ++gg) s += sRed[gg * 16 + p];
        out[(o << 4) + p] = fmaxf(s, 0.f);
    }
}

// ---------------- ct2: ConvT 4x4->16x16 (s=4,p=0), 256->128, relu ---------------
__global__ __launch_bounds__(256) void ct2_fast(
    const float* __restrict__ in, const float* __restrict__ w,
    const float* __restrict__ b, float* __restrict__ out)
{
    __shared__ float sI[1024];
    __shared__ float sW[1024];
    __shared__ float sRed[256];
    const int yy = blockIdx.x, o = blockIdx.y, tid = threadIdx.x;
    const int iy = yy >> 2, ky = yy & 3;
    for (int i = tid; i < 1024; i += 256) {
        int ci = i >> 2, q = i & 3;
        sI[i] = in[(ci << 4) + (iy << 2) + q];
        sW[i] = w[ci * 2048 + (o << 4) + (ky << 2) + q];
    }
    __syncthreads();
    const int xx = tid & 15, g = tid >> 4;
    const int ix = xx >> 2, kx = xx & 3;
    float acc = 0.f;
#pragma unroll 8
    for (int ci = g * 16; ci < g * 16 + 16; ++ci)
        acc = fmaf(sI[(ci << 2) + ix], sW[(ci << 2) + kx], acc);
    sRed[tid] = acc;
    __syncthreads();
    if (g == 0) {
        float s = b[o];
#pragma unroll
        for (int gg = 0; gg < 16; ++gg) s += sRed[gg * 16 + xx];
        out[(o << 8) + (yy << 4) + xx] = fmaxf(s, 0.f);
    }
}

// ---------------- ConvT (k=4,s=2,p=1) Hin->2*Hin, LDS-staged --------------------
__global__ __launch_bounds__(256) void ctup_fast(
    const float* __restrict__ in, const float* __restrict__ w,
    const float* __restrict__ b, float* __restrict__ out,
    int Cin, int Cout, int Hin, int hshift, int relu)
{
    __shared__ float sIn[4608];
    __shared__ float sW[2048];
    __shared__ float sRed[256];
    const int tid = threadIdx.x;
    const int yy = blockIdx.x, o = blockIdx.y;
    const int Hout = Hin << 1;
    const int ST = Hin + 2;
    const int houtshift = hshift + 1;

    const int ky0 = (yy + 1) & 1;
    const int iy0 = (yy + 1 - ky0) >> 1;
    const int iy1 = iy0 - 1;
    const int row_elems = Cin * ST;

    for (int i = tid; i < 2 * row_elems; i += 256) sIn[i] = 0.f;
    __syncthreads();
    const int nload = Cin << hshift;
    if (iy0 < Hin) {
        const float* src = in + ((size_t)iy0 << hshift);
        for (int i = tid; i < nload; i += 256) {
            int ci = i >> hshift, col = i & (Hin - 1);
            sIn[ci * ST + 1 + col] = src[((size_t)ci << (2 * hshift)) + col];
        }
    }
    if (iy1 >= 0) {
        const float* src = in + ((size_t)iy1 << hshift);
        for (int i = tid; i < nload; i += 256) {
            int ci = i >> hshift, col = i & (Hin - 1);
            sIn[row_elems + ci * ST + 1 + col] = src[((size_t)ci << (2 * hshift)) + col];
        }
    }
    for (int i = tid; i < (Cin << 4); i += 256)
        sW[i] = w[(size_t)(i >> 4) * (Cout << 4) + (o << 4) + (i & 15)];
    __syncthreads();

    const int xx = tid & (Hout - 1);
    const int g = tid >> houtshift;
    const int kx0 = (xx + 1) & 1;
    const int ix0 = (xx + 1 - kx0) >> 1;
    const int k00 = (ky0 << 2) + kx0;

    float acc = 0.f;
    const float* in1 = sIn + row_elems;
#pragma unroll 4
    for (int ci = g * 16; ci < g * 16 + 16; ++ci) {
        const int base = ci * ST + ix0;
        const float* wr = &sW[ci << 4];
        float i00 = sIn[base + 1], i01 = sIn[base];
        float i10 = in1[base + 1], i11 = in1[base];
        acc = fmaf(i00, wr[k00], acc);
        acc = fmaf(i01, wr[k00 + 2], acc);
        acc = fmaf(i10, wr[k00 + 8], acc);
        acc = fmaf(i11, wr[k00 + 10], acc);
    }
    sRed[tid] = acc;
    __syncthreads();
    if (g == 0) {
        float s = b[o];
        const int XG = 256 >> houtshift;
        for (int gg = 0; gg < XG; ++gg) s += sRed[(gg << houtshift) + xx];
        out[(size_t)o * Hout * Hout + (size_t)yy * Hout + xx] = relu ? fmaxf(s, 0.f) : s;
    }
}

extern "C" void kernel_launch(void* const* d_in, const int* in_sizes, int n_in,
                              void* d_out, int out_size, void* d_ws, size_t ws_size,
                              hipStream_t stream)
{
    const float* x      = (const float*)d_in[0];
    const float* coords = (const float*)d_in[1];
    const float* Wfc1   = (const float*)d_in[2];
    const float* bfc1   = (const float*)d_in[3];
    const float* Wpos   = (const float*)d_in[4];
    const float* bpos   = (const float*)d_in[5];
    const float* in_w   = (const float*)d_in[6];
    const float* conv_w = (const float*)d_in[7];
    const float* conv_b = (const float*)d_in[8];
    const float* x_w    = (const float*)d_in[9];
    const float* dt_w   = (const float*)d_in[10];
    const float* dt_b   = (const float*)d_in[11];
    const float* A_log  = (const float*)d_in[12];
    const float* Dp     = (const float*)d_in[13];
    const float* out_w  = (const float*)d_in[14];
    const float* rms_w  = (const float*)d_in[15];
    const float* ln_w   = (const float*)d_in[16];
    const float* ln_b   = (const float*)d_in[17];
    const float* Wa1    = (const float*)d_in[18];
    const float* ba1    = (const float*)d_in[19];
    const float* Wa2    = (const float*)d_in[20];
    const float* ba2    = (const float*)d_in[21];
    const float* ct1w   = (const float*)d_in[22];
    const float* ct1b   = (const float*)d_in[23];
    const float* ct2w   = (const float*)d_in[24];
    const float* ct2b   = (const float*)d_in[25];
    const float* ct3w   = (const float*)d_in[26];
    const float* ct3b   = (const float*)d_in[27];
    const float* ct4w   = (const float*)d_in[28];
    const float* ct4b   = (const float*)d_in[29];
    const float* ct5w   = (const float*)d_in[30];
    const float* ct5b   = (const float*)d_in[31];

    // workspace layout (floats)
    float* ws     = (float*)d_ws;
    float* h      = ws;                         // L*DM
    float* hn     = h + (size_t)LSEQ * DM;      // L*DM
    float* xz     = hn + (size_t)LSEQ * DM;     // L*2048 (aliased: fc1/out_proj partials, amx)
    float* xc     = xz + (size_t)LSEQ * 2 * DI; // L*DI
    float* dbc    = xc + (size_t)LSEQ * DI;     // L*64
    float* delta  = dbc + (size_t)LSEQ * 64;    // L*DI
    float* yb     = delta + (size_t)LSEQ * DI;  // L*DI (aliased: x_proj partials)
    float* hf     = yb + (size_t)LSEQ * DI;     // L*DM
    float* scores = hf + (size_t)LSEQ * DM;     // L
    float* wts    = scores + LSEQ;              // L
    float* pooled = wts + LSEQ;                 // DM
    float* c1     = pooled + DM;                // 256*16
    float* c2     = c1 + 256 * 16;              // 128*256
    float* c3     = c2 + 128 * 256;             // 64*1024
    float* c4     = c3 + 64 * 1024;             // 32*4096
    float* aprod  = c4 + 32 * 4096;             // NC*NST*DI (64*16*1024)
    float* hfin   = aprod + (size_t)NC * NST * DI;
    float* carry  = hfin + (size_t)NC * NST * DI;
    float* part   = carry + (size_t)NC * NST * DI;  // 16*DM (pooled partials)
    float* partk  = yb;                          // alias: x_proj split-K partials
    float* skpart = xz;                          // alias: fc1/out_proj 8 partials
    float* amx    = xz;                          // alias: attn pre-act [L,128]

    // fc1 (split-K=8 -> 1024 blocks) -> fused reduce+gelu+pos+rms
    gemm_w<<<dim3(DM / 64, LSEQ / 128, 8), 128, 0, stream>>>(x, 1024, Wfc1, DM, skpart, DM, 1024);
    fc1_fin<<<LSEQ, 256, 0, stream>>>(skpart, bfc1, coords, Wpos, bpos, rms_w, h, hn);

    for (int l = 0; l < 2; ++l) {
        gemm_s<<<dim3(2 * DI / 64, LSEQ / 64, 1), 128, 0, stream>>>(
            hn, DM, in_w + (size_t)l * DM * 2 * DI, 2 * DI, xz, 2 * DI, DM);
        conv_silu_k<<<LSEQ * DI / 4 / 256, 256, 0, stream>>>(
            xz, conv_w + (size_t)l * DI * 4, conv_b + (size_t)l * DI, xc);
        xproj_splitk<<<dim3(8, LSEQ / 64), 256, 0, stream>>>(
            xc, x_w + (size_t)l * DI * 64, partk);
        xproj_reduce<<<LSEQ * 64 / 256, 256, 0, stream>>>(partk, dbc);
        dtproj_k<<<dim3(DI / 64, LSEQ / 64), 256, 0, stream>>>(
            dbc, dt_w + (size_t)l * 32 * DI, dt_b + (size_t)l * DI, delta);
        scan_p1<<<dim3(DI / 128, NC), 128, 0, stream>>>(
            delta, xc, dbc, A_log + (size_t)l * DI * NST, aprod, hfin);
        scan_carry<<<NST * DI / 256, 256, 0, stream>>>(aprod, hfin, carry);
        scan_p2<<<dim3(DI / 128, NC), 128, 0, stream>>>(
            delta, xc, dbc, xz, A_log + (size_t)l * DI * NST, Dp + (size_t)l * DI,
            carry, yb);
        gemm_w<<<dim3(DM / 64, LSEQ / 128, 8), 128, 0, stream>>>(
            yb, DI, out_w + (size_t)l * DI * DM, DM, skpart, DM, 1024);
        if (l == 0)
            skadd_norm<<<LSEQ, 256, 0, stream>>>(skpart, h, rms_w + DM, nullptr, hn, 0);
        else
            skadd_norm<<<LSEQ, 256, 0, stream>>>(skpart, h, ln_w, ln_b, hf, 1);
    }

    gemm64<<<dim3(2, LSEQ / 64), 256, 0, stream>>>(hf, DM, Wa1, 128, amx, 128, DM, 0);
    attn_fin<<<LSEQ / 4, 256, 0, stream>>>(amx, ba1, Wa2, ba2, scores);
    softmax_k<<<1, 1024, 0, stream>>>(scores, wts);
    pooled_p1<<<dim3(2, 16), 256, 0, stream>>>(wts, hf, part);
    pooled_p2<<<2, 256, 0, stream>>>(part, pooled);

    ct1_fast<<<256, 256, 0, stream>>>(pooled, ct1w, ct1b, c1);
    ct2_fast<<<dim3(16, 128), 256, 0, stream>>>(c1, ct2w, ct2b, c2);
    ctup_fast<<<dim3(32, 64), 256, 0, stream>>>(c2, ct3w, ct3b, c3, 128, 64, 16, 4, 1);
    ctup_fast<<<dim3(64, 32), 256, 0, stream>>>(c3, ct4w, ct4b, c4, 64, 32, 32, 5, 1);
    ctup_fast<<<dim3(128, 11), 256, 0, stream>>>(c4, ct5w, ct5b, (float*)d_out, 32, 11, 64, 6, 0);
}